// Round 7
// baseline (161.160 us; speedup 1.0000x reference)
//
#include <hip/hip_runtime.h>
#include <stdint.h>

#define TH 8
#define W_ 1024
#define H_ 1024

typedef __attribute__((address_space(3))) uint32_t lds_u32;
typedef __attribute__((address_space(1))) const uint32_t glb_u32;

// async global->LDS DMA, 16B per lane. LDS dest: wave-uniform base + lane*16.
// Casts go through uintptr_t: direct pointer casts that change address space
// do not compile (Round-6 failure cause).
__device__ __forceinline__ void dma16(const float* g, float* l) {
    __builtin_amdgcn_global_load_lds((glb_u32*)(uintptr_t)g,
                                     (lds_u32*)(uintptr_t)l, 16, 0, 0);
}

__device__ __forceinline__ float wexp1(float zp, float iz, float kd, float kspat) {
    const float u = fmaf(zp, iz, -1.0f);
    return __builtin_amdgcn_exp2f(fmaf(u * kd, u, kspat));
}

// 5-tap depth-guided blur of (b,d) around center; taps m2,m1,[c],p1,p2
__device__ __forceinline__ void blur5(
    float zm2, float zm1, float zc, float zp1, float zp2,
    float bm2, float bm1, float bc, float bp1, float bp2,
    float dm2, float dm1, float dc, float dp1, float dp2,
    float kd, float ks1, float ks4,
    float& ob, float& od)
{
    const float iz = __builtin_amdgcn_rcpf(zc);
    const float w0 = wexp1(zm2, iz, kd, ks4);
    const float w1 = wexp1(zm1, iz, kd, ks1);
    const float w3 = wexp1(zp1, iz, kd, ks1);
    const float w4 = wexp1(zp2, iz, kd, ks4);
    const float wr = __builtin_amdgcn_rcpf(1.0f + w0 + w1 + w3 + w4);
    ob = fmaf(w0, bm2, fmaf(w1, bm1, fmaf(w3, bp1, fmaf(w4, bp2, bc)))) * wr;
    od = fmaf(w0, dm2, fmaf(w1, dm1, fmaf(w3, dp1, fmaf(w4, dp2, dc)))) * wr;
}

__device__ __forceinline__ float blend1(float bc, float dc, float bm, float dm,
                                        float de, float dke, float ce) {
    const float devb = __builtin_amdgcn_exp2f(
        de * __builtin_amdgcn_logf(fmaxf(fabsf(bc - bm), 1e-8f))) * ce;
    const float devd = fmaxf(__builtin_amdgcn_exp2f(
        de * __builtin_amdgcn_logf(fmaxf(fabsf(dc - dm), 1e-8f))), dke);
    const float wr = __builtin_amdgcn_rcpf(devb + devd);
    return fmaf(devd, bc, devb * dc) * wr;
}

// issue 3 async DMAs for row gy (clamped; OOB rows load a valid row whose data
// is never consumed — keeps per-wave vmcnt counts uniform across all blocks).
__device__ __forceinline__ void dma_row(
    int gy, const float* __restrict__ bB, const float* __restrict__ dB,
    const float* __restrict__ zB,
    float* sZs, float* sBs, float* sDs, int c, int wb)
{
    const int gyc = min(max(gy, 0), H_ - 1);
    const size_t ro = (size_t)gyc * W_;
    dma16(zB + ro + c, sZs + wb);
    dma16(bB + ro + c, sBs + wb);
    dma16(dB + ro + c, sDs + wb);
}

// pure-VALU horizontal blur reading taps from an LDS row slot.
// Halo cols come free from neighbor lanes' staging (no global halo loads).
__device__ __forceinline__ void hblur_lds(
    int gy, const float* sZs, const float* sBs, const float* sDs,
    int c, int colL2, int colR2, bool eL, bool eR,
    float kd, float ks1, float ks4,
    float4& sb, float4& sd, float4& sz)
{
    if ((unsigned)gy < (unsigned)H_) {   // block-uniform
        float2 lz = *(const float2*)(sZs + colL2);
        const float4 cz = *(const float4*)(sZs + c);
        float2 rz = *(const float2*)(sZs + colR2);
        const float2 lb = *(const float2*)(sBs + colL2);
        const float4 cb = *(const float4*)(sBs + c);
        const float2 rb = *(const float2*)(sBs + colR2);
        const float2 ld = *(const float2*)(sDs + colL2);
        const float4 cd = *(const float4*)(sDs + c);
        const float2 rd = *(const float2*)(sDs + colR2);
        // image-edge taps: poison depth -> w = 0 exactly (matches zero-pad ref)
        if (eL) { lz.x = 1e18f; lz.y = 1e18f; }
        if (eR) { rz.x = 1e18f; rz.y = 1e18f; }
        blur5(lz.x, lz.y, cz.x, cz.y, cz.z,  lb.x, lb.y, cb.x, cb.y, cb.z,
              ld.x, ld.y, cd.x, cd.y, cd.z,  kd, ks1, ks4, sb.x, sd.x);
        blur5(lz.y, cz.x, cz.y, cz.z, cz.w,  lb.y, cb.x, cb.y, cb.z, cb.w,
              ld.y, cd.x, cd.y, cd.z, cd.w,  kd, ks1, ks4, sb.y, sd.y);
        blur5(cz.x, cz.y, cz.z, cz.w, rz.x,  cb.x, cb.y, cb.z, cb.w, rb.x,
              cd.x, cd.y, cd.z, cd.w, rd.x,  kd, ks1, ks4, sb.z, sd.z);
        blur5(cz.y, cz.z, cz.w, rz.x, rz.y,  cb.y, cb.z, cb.w, rb.x, rb.y,
              cd.y, cd.z, cd.w, rd.x, rd.y,  kd, ks1, ks4, sb.w, sd.w);
        sz = cz;
    } else {
        // zero row: vertical tap z=0 -> t=-1 -> w underflows to 0 exact
        sb = make_float4(0.f, 0.f, 0.f, 0.f);
        sd = make_float4(0.f, 0.f, 0.f, 0.f);
        sz = make_float4(0.f, 0.f, 0.f, 0.f);
    }
}

// Phase boundary: counted vmcnt (never 0 in steady state -> next row's DMA
// stays in flight across the barrier), raw s_barrier, compiler fence so
// ds_reads cannot hoist above the barrier.
#define PHASE(N)                                                              \
    asm volatile("s_waitcnt vmcnt(" #N ")" ::: "memory");                     \
    __builtin_amdgcn_s_barrier();                                             \
    asm volatile("" ::: "memory");

// warm-up step K: DMA row (y0+K-1) -> slot DS; wait row (y0+K-2) in slot CS;
// h-blur it into pipeline slot S.
#define WSTEP(S, CS, DS, K, N)                                                \
  {                                                                           \
    dma_row(y0 + (K) - 1, bB, dB, zB, sZ[DS], sB[DS], sD[DS], c, wb);         \
    PHASE(N)                                                                  \
    hblur_lds(y0 + (K) - 2, sZ[CS], sB[CS], sD[CS], c, colL2, colR2, eL, eR,  \
              kd, ks1, ks4, pb[S], pd[S], pz[S]);                             \
  }

// full step K: blend re-reads issued FIRST and fenced so they stay OLDER than
// the DMAs in the vmcnt FIFO (else the compiler's wait before blend use would
// be vmcnt(0) and drain the in-flight DMAs); then DMA; then phase boundary;
// then h-blur + v-blur + blend + store.
#define FSTEP(S, S0, S1, S2, S3, S4, CS, DS, K, N, DODMA)                     \
  {                                                                           \
    const size_t oo = (size_t)(y0 + (K) - 4) * W_ + c;                        \
    const float4 rb4 = *(const float4*)(bB + oo);                             \
    const float4 rd4 = *(const float4*)(dB + oo);                             \
    asm volatile("" ::: "memory");  /* pin: blend loads before DMAs in FIFO */\
    if (DODMA) dma_row(y0 + (K) - 1, bB, dB, zB, sZ[DS], sB[DS], sD[DS], c, wb); \
    PHASE(N)                                                                  \
    hblur_lds(y0 + (K) - 2, sZ[CS], sB[CS], sD[CS], c, colL2, colR2, eL, eR,  \
              kd, ks1, ks4, pb[S], pd[S], pz[S]);                             \
    float4 bm, dm;                                                            \
    blur5(pz[S0].x, pz[S1].x, pz[S2].x, pz[S3].x, pz[S4].x,                   \
          pb[S0].x, pb[S1].x, pb[S2].x, pb[S3].x, pb[S4].x,                   \
          pd[S0].x, pd[S1].x, pd[S2].x, pd[S3].x, pd[S4].x,                   \
          kd, ks1, ks4, bm.x, dm.x);                                          \
    blur5(pz[S0].y, pz[S1].y, pz[S2].y, pz[S3].y, pz[S4].y,                   \
          pb[S0].y, pb[S1].y, pb[S2].y, pb[S3].y, pb[S4].y,                   \
          pd[S0].y, pd[S1].y, pd[S2].y, pd[S3].y, pd[S4].y,                   \
          kd, ks1, ks4, bm.y, dm.y);                                          \
    blur5(pz[S0].z, pz[S1].z, pz[S2].z, pz[S3].z, pz[S4].z,                   \
          pb[S0].z, pb[S1].z, pb[S2].z, pb[S3].z, pb[S4].z,                   \
          pd[S0].z, pd[S1].z, pd[S2].z, pd[S3].z, pd[S4].z,                   \
          kd, ks1, ks4, bm.z, dm.z);                                          \
    blur5(pz[S0].w, pz[S1].w, pz[S2].w, pz[S3].w, pz[S4].w,                   \
          pb[S0].w, pb[S1].w, pb[S2].w, pb[S3].w, pb[S4].w,                   \
          pd[S0].w, pd[S1].w, pd[S2].w, pd[S3].w, pd[S4].w,                   \
          kd, ks1, ks4, bm.w, dm.w);                                          \
    float4 res;                                                               \
    res.x = blend1(rb4.x, rd4.x, bm.x, dm.x, de, dke, ce);                    \
    res.y = blend1(rb4.y, rd4.y, bm.y, dm.y, de, dke, ce);                    \
    res.z = blend1(rb4.z, rd4.z, bm.z, dm.z, de, dke, ce);                    \
    res.w = blend1(rb4.w, rd4.w, bm.w, dm.w, de, dke, ce);                    \
    *(float4*)(outB + oo) = res;                                              \
  }

// LDS-staged pipeline (Rounds 2-5 proved the compiler will not keep
// register-resident loads in flight: VGPR pinned at 60, prefetch sunk to use).
// global_load_lds costs zero VGPR, so the compiler cannot defeat it.
// 3 row-slots x 3 arrays x 4KB = 36KB LDS -> 4 blocks/CU.
// vmcnt ledger (per-wave FIFO, store included), steady state at PHASE:
// [D_{K-1}x3, store_{K-1}, rb4, rd4, D_Kx3] = 9 -> vmcnt(6) retires exactly
// D_{K-1}x3; D_K stays in flight across the barrier. Warmup: 3+3 -> vmcnt(3).
// Tail (no DMA): [D_10x3, store, rb4, rd4] = 6 -> vmcnt(3) retires D_10x3.
__global__ __launch_bounds__(256, 4)
void bilateral_fused(const float* __restrict__ bright,
                     const float* __restrict__ dark,
                     const float* __restrict__ depths,
                     const float* __restrict__ p_dv,
                     const float* __restrict__ p_sv,
                     const float* __restrict__ p_de,
                     const float* __restrict__ p_deps,
                     const float* __restrict__ p_ce,
                     float* __restrict__ out)
{
    __shared__ __attribute__((aligned(16))) float sZ[3][W_];
    __shared__ __attribute__((aligned(16))) float sB[3][W_];
    __shared__ __attribute__((aligned(16))) float sD[3][W_];

    const float LOG2E = 1.44269504088896340736f;
    const float kd  = -LOG2E / (2.0f * p_dv[0]);   // ~ -1803
    const float ks  = -LOG2E / (2.0f * p_sv[0]);
    const float de  = p_de[0];
    const float dke = p_deps[0];
    const float ce  = p_ce[0];
    const float ks1 = ks;
    const float ks4 = 4.0f * ks;

    const int t  = threadIdx.x;           // 0..255
    const int c  = 4 * t;                 // cols c..c+3 (= DMA lane offset)
    const int wb = (t >> 6) << 8;         // wave's 256-float span in a row slot
    const int y0 = blockIdx.y * TH;

    const size_t plane = (size_t)H_ * W_;
    const float* bB = bright + (size_t)blockIdx.z * plane;
    const float* dB = dark   + (size_t)blockIdx.z * plane;
    const float* zB = depths + (size_t)blockIdx.z * plane;
    float*     outB = out    + (size_t)blockIdx.z * plane;

    const int  colL2 = max(c - 2, 0);        // float2 [c-2,c-1], 8B aligned
    const int  colR2 = min(c + 4, W_ - 2);   // float2 [c+4,c+5]
    const bool eL = (c == 0);
    const bool eR = (c + 4 >= W_);

    // 5-deep register pipeline of h-blurred rows + center depths
    float4 pb[5], pd[5], pz[5];

    // prologue: DMA first staged row (y0-2) into slot 0
    dma_row(y0 - 2, bB, dB, zB, sZ[0], sB[0], sD[0], c, wb);

    // warm-up steps 0..3: stage rows y0-2 .. y0+1 into pipeline slots 0..3
    WSTEP(0, 0, 1, 0, 3)
    WSTEP(1, 1, 2, 1, 3)
    WSTEP(2, 2, 0, 2, 3)
    WSTEP(3, 0, 1, 3, 3)

    // steady state steps 4..11: outputs rows y0 .. y0+7
    FSTEP(4, 0, 1, 2, 3, 4,  1, 2,  4, 5, 1)
    FSTEP(0, 1, 2, 3, 4, 0,  2, 0,  5, 6, 1)
    FSTEP(1, 2, 3, 4, 0, 1,  0, 1,  6, 6, 1)
    FSTEP(2, 3, 4, 0, 1, 2,  1, 2,  7, 6, 1)
    FSTEP(3, 4, 0, 1, 2, 3,  2, 0,  8, 6, 1)
    FSTEP(4, 0, 1, 2, 3, 4,  0, 1,  9, 6, 1)
    FSTEP(0, 1, 2, 3, 4, 0,  1, 2, 10, 6, 1)
    FSTEP(1, 2, 3, 4, 0, 1,  2, 0, 11, 3, 0)   // last: no DMA
}

extern "C" void kernel_launch(void* const* d_in, const int* in_sizes, int n_in,
                              void* d_out, int out_size, void* d_ws, size_t ws_size,
                              hipStream_t stream)
{
    const float* bright = (const float*)d_in[0];
    const float* dark   = (const float*)d_in[1];
    const float* depths = (const float*)d_in[2];
    const float* p_dv   = (const float*)d_in[3];
    const float* p_sv   = (const float*)d_in[4];
    const float* p_de   = (const float*)d_in[5];
    const float* p_deps = (const float*)d_in[6];
    const float* p_ce   = (const float*)d_in[7];
    float* out = (float*)d_out;

    const int B = in_sizes[0] / (H_ * W_);

    dim3 grid(1, H_ / TH, B);
    dim3 block(256);
    bilateral_fused<<<grid, block, 0, stream>>>(bright, dark, depths,
                                                p_dv, p_sv, p_de, p_deps, p_ce,
                                                out);
}